// Round 7
// baseline (11541.276 us; speedup 1.0000x reference)
//
#include <hip/hip_runtime.h>

#define NN 512
#define DD 32
#define TT 8192

typedef float v4f __attribute__((ext_vector_type(4)));
typedef __attribute__((address_space(3))) float lds_f;
typedef __attribute__((address_space(3))) void lds_v;
typedef const __attribute__((address_space(1))) void glb_v;

constexpr float F_OMEGA = 10.0f;
constexpr float F_DT = 1e-3f;
constexpr float F_TWO_PI = 6.28318530717958647692f;
constexpr float F_INV_TWO_PI = 0.15915494309189533577f;

// Barrier waiting LDS/SMEM only (lgkmcnt), never vmcnt: glds prefetches and
// output stores stay in flight across the per-step sync.
__device__ __forceinline__ void barrier_lgkm() {
    asm volatile("s_waitcnt lgkmcnt(0)\n\ts_barrier" ::: "memory");
}

// Async global->LDS stage, vmcnt-tracked (wave-uniform LDS base + lane*4).
__device__ __forceinline__ void glds4(const float* g, lds_f* dst) {
    __builtin_amdgcn_global_load_lds((glb_v*)g, (lds_v*)dst, 4, 0, 0);
}

// Asm-laundered LDS reads: not scalarizable, not hoistable above the tied
// lgkm wait, and invisible to alias analysis (no conservative vmcnt drain).
#define DSR128(dst, addr, off) \
    asm volatile("ds_read_b128 %0, %1 offset:" #off : "=v"(dst) : "v"(addr))
#define DSR32(dst, addr, off) \
    asm volatile("ds_read_b32 %0, %1 offset:" #off : "=v"(dst) : "v"(addr))

// One step of a DPP-based wave64 reduction: x += dpp_move(x).
#define DPP_ADD(x, ctrl, rmask)                                                 \
    {                                                                           \
        int _t = __builtin_amdgcn_update_dpp(0, __float_as_int(x),              \
                                             (ctrl), (rmask), 0xf, true);       \
        (x) += __int_as_float(_t);                                              \
    }

__device__ __forceinline__ float wave_reduce_to_lane63(float x) {
    DPP_ADD(x, 0xB1, 0xf);   // + xor1
    DPP_ADD(x, 0x4E, 0xf);   // + xor2
    DPP_ADD(x, 0x141, 0xf);  // + xor4
    DPP_ADD(x, 0x140, 0xf);  // + xor8
    DPP_ADD(x, 0x142, 0xa);  // row_bcast15
    DPP_ADD(x, 0x143, 0xc);  // row_bcast31
    return x;                // lane 63 = full wave sum
}

__device__ __forceinline__ float hsum4(v4f a) {
    return (a.x + a.y) + (a.z + a.w);
}

__global__ __launch_bounds__(1024, 4) void deerskin(
    const float* __restrict__ Xr, const float* __restrict__ Xi,
    const float* __restrict__ Tg,
    const float* __restrict__ W0r, const float* __restrict__ W0i,
    const float* __restrict__ Phi0, const float* __restrict__ Beta0,
    float* __restrict__ outs, float* __restrict__ betas, float* __restrict__ gammas)
{
    // 3 x-staging buffers: [0..31]=xr, [32..63]=xi, [64]=tgt (288B each).
    __shared__ __align__(16) float xbuf[3][72];
    __shared__ __align__(16) float sP[32];   // double-buffered 16 wave-partials

    const int tid = threadIdx.x;
    const int n = tid >> 1;          // neuron
    const int h = tid & 1;           // d-half: h*16 .. h*16+15
    const int lane = tid & 63;
    const int wid = tid >> 6;        // 0..15

    // Half W row in registers: 16 complex = 32 VGPRs.
    v4f wr4[4], wi4[4];
    {
        const v4f* wr0 = (const v4f*)(W0r + n * DD + h * 16);
        const v4f* wi0 = (const v4f*)(W0i + n * DD + h * 16);
#pragma unroll
        for (int j = 0; j < 4; ++j) { wr4[j] = wr0[j]; wi4[j] = wi0[j]; }
    }
    // Per-neuron state, duplicated identically in both half-threads.
    float phi = Phi0[n];
    float beta = Beta0[n];
    float lt = 0.0f;
    float err = 0.0f;

    // glds source for wave 0: lanes 0..31 -> Xr row, 32..63 -> Xi row.
    const float* xsrc = ((lane < 32) ? Xr : Xi) + (lane & 31);

    lds_f* pcur = (lds_f*)&xbuf[0][0];
    lds_f* pnxt = (lds_f*)&xbuf[1][0];
    lds_f* pfut = (lds_f*)&xbuf[2][0];

    // ---- prologue: stage x(0), x(1); wave 0 drains, all sync ----
    if (wid == 0) {
        glds4(xsrc, pcur);
        glds4(xsrc + DD, pnxt);
        if (lane == 0) {
            glds4(Tg, pcur + 64);
            glds4(Tg + 1, pnxt + 64);
        }
        asm volatile("s_waitcnt vmcnt(0)" ::: "memory");
    }
    barrier_lgkm();

    for (int t = 0; t < TT; ++t) {
        // ---- 1. stage x(t+2) (wave 0; drained by the counted wait below) ----
        if (wid == 0) {
            int tf = t + 2; tf = (tf < TT) ? tf : (TT - 1);
            glds4(xsrc + (size_t)tf * DD, pfut);
            if (lane == 0) glds4(Tg + tf, pfut + 64);
        }

        // ---- 2. x-independent precompute ----
        const float gamma = __expf(-0.5f * beta);
        const float dtl = gamma * F_DT;
        lt += dtl;
        const float theta = fmaf(F_OMEGA, lt, phi);
        float rev = theta * F_INV_TWO_PI;
        rev -= floorf(rev);
        const float s = __builtin_amdgcn_sinf(rev);
        const float c = __builtin_amdgcn_cosf(rev);
        const float a_sA = 1.0f - __expf(-2.0f * F_DT * (gamma + 1e-6f));
        const float a_sB = 1.0f - __expf(-F_DT / 0.03f);   // constant-folded

        // ---- 3. this thread's d-half of x(t) from LDS ----
        const unsigned lcur = (unsigned)(unsigned long long)pcur;
        const unsigned lhalf = lcur + (unsigned)(h * 64);   // byte offset h*16 floats
        v4f cr[4], ci[4];
        float tgt;
        DSR128(cr[0], lhalf, 0);   DSR128(cr[1], lhalf, 16);
        DSR128(cr[2], lhalf, 32);  DSR128(cr[3], lhalf, 48);
        DSR128(ci[0], lhalf, 128); DSR128(ci[1], lhalf, 144);
        DSR128(ci[2], lhalf, 160); DSR128(ci[3], lhalf, 176);
        DSR32(tgt, lcur, 256);
        asm volatile("s_waitcnt lgkmcnt(0)"
            : "+v"(cr[0]), "+v"(cr[1]), "+v"(cr[2]), "+v"(cr[3]),
              "+v"(ci[0]), "+v"(ci[1]), "+v"(ci[2]), "+v"(ci[3]),
              "+v"(tgt) :: "memory");

        // ---- 4. Z half-matvec (4 packed chains over 16 taps) + pair-add ----
        v4f Arr = {0,0,0,0}, Aii = {0,0,0,0}, Ari = {0,0,0,0}, Air = {0,0,0,0};
#pragma unroll
        for (int j = 0; j < 4; ++j) {
            Arr += wr4[j] * cr[j];
            Aii += wi4[j] * ci[j];
            Ari += wr4[j] * ci[j];
            Air += wi4[j] * cr[j];
        }
        float zr = hsum4(Arr) - hsum4(Aii);
        float zi = hsum4(Ari) + hsum4(Air);
        // full Z = sum of the two halves (lanes 2k, 2k+1)
        DPP_ADD(zr, 0xB1, 0xf);
        DPP_ADD(zi, 0xB1, 0xf);

        // Y = |Z| * relu(cos(theta - angle(Z))) == relu(zr*cos + zi*sin)
        const float Y = fmaxf(fmaf(zr, c, zi * s), 0.0f);

        // ---- 5. reduce 512 -> 1: mask half-1 (its Y duplicates half-0's),
        // DPP wave sum (32 neurons/wave), 16 partials via LDS ----
        float v = h ? 0.0f : (Y * c);
        v = wave_reduce_to_lane63(v);
        if (lane == 63) sP[((t & 1) << 4) + wid] = v;

        // ---- 6. out-independent precompute (off the post-barrier path) ----
        const float inv_t = 1.0f / (fabsf(tgt) + 0.01f);
        const float yy = Y * Y;
        const float g = 0.05f * Y * dtl;
        phi += (2.0f / (float)NN) * (-tgt * s) * dtl;
        phi = phi - F_TWO_PI * floorf(phi * F_INV_TWO_PI);

        // ---- 7. counted drain of glds(t+1) (wave 0), then sync.
        // Newer than glds(t+1): glds(t+2) x2 + store-instrs(t-1) x3 = 5.
        if (wid == 0) asm volatile("s_waitcnt vmcnt(5)" ::: "memory");
        barrier_lgkm();

        // ---- 8. out + short scalar feedback chain ----
        const float4* sp4 = (const float4*)(sP + ((t & 1) << 4));
        const float4 p0 = sp4[0], p1 = sp4[1], p2 = sp4[2], p3 = sp4[3];
        const float o01 = ((p0.x + p0.y) + (p0.z + p0.w)) +
                          ((p1.x + p1.y) + (p1.z + p1.w));
        const float o23 = ((p2.x + p2.y) + (p2.z + p2.w)) +
                          ((p3.x + p3.y) + (p3.z + p3.w));
        const float out = o01 + o23;

        const float raw = fabsf(tgt - out);
        err = 0.99f * err + 0.01f * raw;
        const float rel = err * inv_t;
        const float btg = 3.5f * __expf(-5.0f * rel);
        const float a_s = (btg > beta) ? a_sA : a_sB;
        float bnew = beta + a_s * (btg - beta);
        bnew = fminf(fmaxf(bnew, 0.005f), 5.0f);

        // ---- 9. W = W*(1 - (bnew*yy)*dtl) + g*x (packed, same FP order) ----
        const float k = (bnew * yy) * dtl;
        const float m1 = 1.0f - k;
        const v4f m1v = {m1, m1, m1, m1};
        const v4f gv = {g, g, g, g};
#pragma unroll
        for (int j = 0; j < 4; ++j) {
            wr4[j] = wr4[j] * m1v + gv * cr[j];
            wi4[j] = wi4[j] * m1v + gv * ci[j];
        }

        // ---- 10. outputs: 3 store-instrs per wave per step (uniform vmcnt).
        // h==0 lanes cover all 512 neurons exactly once; outs via lane 63 of
        // every wave (identical value).
        if (h == 0) {
            gammas[t * NN + n] = gamma;   // gamma from OLD beta, per reference
            betas[t * NN + n] = bnew;
        }
        if (lane == 63) outs[t] = out;
        beta = bnew;

        // ---- 11. rotate staging buffers ----
        lds_f* tmp = pcur; pcur = pnxt; pnxt = pfut; pfut = tmp;
    }
}

extern "C" void kernel_launch(void* const* d_in, const int* in_sizes, int n_in,
                              void* d_out, int out_size, void* d_ws, size_t ws_size,
                              hipStream_t stream) {
    const float* Xr    = (const float*)d_in[0];   // [T, D]
    const float* Xi    = (const float*)d_in[1];   // [T, D]
    const float* Tg    = (const float*)d_in[2];   // [T]
    const float* W0r   = (const float*)d_in[3];   // [N, D]
    const float* W0i   = (const float*)d_in[4];   // [N, D]
    const float* Phi0  = (const float*)d_in[5];   // [N]
    const float* Beta0 = (const float*)d_in[6];   // [N]

    float* outs   = (float*)d_out;                // [T]
    float* betas  = outs + TT;                    // [T, N]
    float* gammas = betas + (size_t)TT * NN;      // [T, N]

    deerskin<<<1, 1024, 0, stream>>>(Xr, Xi, Tg, W0r, W0i, Phi0, Beta0,
                                     outs, betas, gammas);
}